// Round 6
// baseline (55.398 us; speedup 1.0000x reference)
//
#include <hip/hip_runtime.h>
#include <stdint.h>

#define IN_F 8192
#define OUT_F 8192
#define BATCH 8
// Permuted x sign-bit layout, matched to the gemv's lane order:
//   word[(b*4 + m)*64 + l], bit (4*i + k) = signbit(x[b*8192 + m*2048 + i*256 + l*4 + k])
#define XPW (BATCH * 4 * 64)  // 2048 words = 8 KB

typedef unsigned int u32x4 __attribute__((ext_vector_type(4)));

__global__ __launch_bounds__(256) void pack_sign_perm(
    const u32x4* __restrict__ x, uint32_t* __restrict__ xp) {
  const int t = blockIdx.x * 256 + threadIdx.x;  // 0..2047
  const int b = t >> 8;
  const int m = (t >> 6) & 3;
  const int l = t & 63;
  const u32x4* base = x + (b * IN_F + m * 2048 + l * 4) / 4;
  uint32_t w = 0;
#pragma unroll
  for (int i = 0; i < 8; ++i) {
    u32x4 u = base[i * 64];
    uint32_t nib = (u.x >> 31) | ((u.y >> 31) << 1) |
                   ((u.z >> 31) << 2) | ((u.w >> 31) << 3);
    w |= nib << (4 * i);
  }
  xp[t] = w;
}

// One wave per output row, no LDS, no barrier. __launch_bounds__(256,8)
// forces VGPR<=64 so all 32 waves/CU stay resident -> max outstanding
// NT-load pressure for the HBM stream.
__global__ __launch_bounds__(256, 8) void ternary_gemv4(
    const u32x4* __restrict__ W, const uint32_t* __restrict__ xp,
    const float* __restrict__ bias, float* __restrict__ out) {
  const int warp = threadIdx.x >> 6;
  const int lane = threadIdx.x & 63;
  const int row = blockIdx.x * 4 + warp;
  const u32x4* wrow = W + (size_t)row * (IN_F / 4);

  int cnt[BATCH] = {0, 0, 0, 0, 0, 0, 0, 0};

#pragma unroll
  for (int m = 0; m < 4; ++m) {
    u32x4 u[8];
#pragma unroll
    for (int i = 0; i < 8; ++i)
      u[i] = __builtin_nontemporal_load(&wrow[m * 512 + i * 64 + lane]);

    uint32_t xn[BATCH];
#pragma unroll
    for (int b = 0; b < BATCH; ++b)
      xn[b] = xp[(b * 4 + m) * 64 + lane];

    uint32_t wn = 0;
#pragma unroll
    for (int i = 0; i < 8; ++i) {
      uint32_t nib = (u[i].x >> 31) | ((u[i].y >> 31) << 1) |
                     ((u[i].z >> 31) << 2) | ((u[i].w >> 31) << 3);
      wn |= nib << (4 * i);
    }

#pragma unroll
    for (int b = 0; b < BATCH; ++b)
      cnt[b] += __popc(wn ^ xn[b]);
  }

  // Wave-level reduce of the 8 mismatch counts.
#pragma unroll
  for (int b = 0; b < BATCH; ++b) {
#pragma unroll
    for (int off = 32; off > 0; off >>= 1)
      cnt[b] += __shfl_down(cnt[b], off);
  }

  if (lane == 0) {
    const float bv = bias[row];
#pragma unroll
    for (int b = 0; b < BATCH; ++b)
      out[(size_t)b * OUT_F + row] = (float)(IN_F - 2 * cnt[b]) + bv;
  }
}

extern "C" void kernel_launch(void* const* d_in, const int* in_sizes, int n_in,
                              void* d_out, int out_size, void* d_ws, size_t ws_size,
                              hipStream_t stream) {
  const u32x4* x = (const u32x4*)d_in[0];  // fp32 bits of input [8,8192]
  const u32x4* W = (const u32x4*)d_in[1];  // fp32 bits of weight [8192,8192]
  const float* bias = (const float*)d_in[2];
  float* out = (float*)d_out;              // [8,8192]
  uint32_t* xp = (uint32_t*)d_ws;          // 8 KB permuted sign bits

  pack_sign_perm<<<XPW / 256, 256, 0, stream>>>(x, xp);
  ternary_gemv4<<<OUT_F / 4, 256, 0, stream>>>(W, xp, bias, out);
}

// Round 7
// 49.949 us; speedup vs baseline: 1.1091x; 1.1091x over previous
//
#include <hip/hip_runtime.h>
#include <stdint.h>

#define IN_F 8192
#define OUT_F 8192
#define BATCH 8
// Permuted x sign-bit layout, matched to the gemv's lane order:
//   word[(b*4 + m)*64 + l], bit (4*i + k) = signbit(x[b*8192 + m*2048 + i*256 + l*4 + k])
#define XPW (BATCH * 4 * 64)  // 2048 words = 8 KB

typedef unsigned int u32x4 __attribute__((ext_vector_type(4)));

__global__ __launch_bounds__(256) void pack_sign_perm(
    const u32x4* __restrict__ x, uint32_t* __restrict__ xp) {
  const int t = blockIdx.x * 256 + threadIdx.x;  // 0..2047
  const int b = t >> 8;
  const int m = (t >> 6) & 3;
  const int l = t & 63;
  const u32x4* base = x + (b * IN_F + m * 2048 + l * 4) / 4;
  uint32_t w = 0;
#pragma unroll
  for (int i = 0; i < 8; ++i) {
    u32x4 u = base[i * 64];
    uint32_t nib = (u.x >> 31) | ((u.y >> 31) << 1) |
                   ((u.z >> 31) << 2) | ((u.w >> 31) << 3);
    w |= nib << (4 * i);
  }
  xp[t] = w;
}

// One wave per output row, no LDS, no barrier. Double-buffered W load
// groups: issue the next 8 NT uint4 loads before consuming the current
// group, doubling per-wave outstanding HBM bytes. All indexing into u[][]
// is compile-time constant (loops fully unrolled) so it stays in VGPRs.
__global__ __launch_bounds__(256) void ternary_gemv5(
    const u32x4* __restrict__ W, const uint32_t* __restrict__ xp,
    const float* __restrict__ bias, float* __restrict__ out) {
  const int warp = threadIdx.x >> 6;
  const int lane = threadIdx.x & 63;
  const int row = blockIdx.x * 4 + warp;
  const u32x4* wrow = W + (size_t)row * (IN_F / 4);

  int cnt[BATCH] = {0, 0, 0, 0, 0, 0, 0, 0};

  u32x4 u[2][8];
  // Prologue: group 0 in flight.
#pragma unroll
  for (int i = 0; i < 8; ++i)
    u[0][i] = __builtin_nontemporal_load(&wrow[i * 64 + lane]);

#pragma unroll
  for (int m = 0; m < 4; ++m) {
    // Issue group m+1 before consuming group m.
    if (m < 3) {
#pragma unroll
      for (int i = 0; i < 8; ++i)
        u[(m + 1) & 1][i] =
            __builtin_nontemporal_load(&wrow[(m + 1) * 512 + i * 64 + lane]);
    }

    uint32_t xn[BATCH];
#pragma unroll
    for (int b = 0; b < BATCH; ++b)
      xn[b] = xp[(b * 4 + m) * 64 + lane];

    uint32_t wn = 0;
#pragma unroll
    for (int i = 0; i < 8; ++i) {
      const u32x4 v = u[m & 1][i];
      uint32_t nib = (v.x >> 31) | ((v.y >> 31) << 1) |
                     ((v.z >> 31) << 2) | ((v.w >> 31) << 3);
      wn |= nib << (4 * i);
    }

#pragma unroll
    for (int b = 0; b < BATCH; ++b)
      cnt[b] += __popc(wn ^ xn[b]);
  }

  // Wave-level reduce of the 8 mismatch counts.
#pragma unroll
  for (int b = 0; b < BATCH; ++b) {
#pragma unroll
    for (int off = 32; off > 0; off >>= 1)
      cnt[b] += __shfl_down(cnt[b], off);
  }

  if (lane == 0) {
    const float bv = bias[row];
#pragma unroll
    for (int b = 0; b < BATCH; ++b)
      out[(size_t)b * OUT_F + row] = (float)(IN_F - 2 * cnt[b]) + bv;
  }
}

extern "C" void kernel_launch(void* const* d_in, const int* in_sizes, int n_in,
                              void* d_out, int out_size, void* d_ws, size_t ws_size,
                              hipStream_t stream) {
  const u32x4* x = (const u32x4*)d_in[0];  // fp32 bits of input [8,8192]
  const u32x4* W = (const u32x4*)d_in[1];  // fp32 bits of weight [8192,8192]
  const float* bias = (const float*)d_in[2];
  float* out = (float*)d_out;              // [8,8192]
  uint32_t* xp = (uint32_t*)d_ws;          // 8 KB permuted sign bits

  pack_sign_perm<<<XPW / 256, 256, 0, stream>>>(x, xp);
  ternary_gemv5<<<OUT_F / 4, 256, 0, stream>>>(W, xp, bias, out);
}